// Round 13
// baseline (2297.665 us; speedup 1.0000x reference)
//
#include <hip/hip_runtime.h>
#include <cstdint>

typedef unsigned short bf16u;
typedef __attribute__((ext_vector_type(8))) short short8;
typedef __attribute__((ext_vector_type(4))) short short4v;
typedef __attribute__((ext_vector_type(4))) float f32x4;

#define SEQ   2048
#define EMB   2048
#define NHEAD 16
#define NKV   4
#define DKH   128
#define HIDN  8192
#define NVOC  32000
#define NLAY  4
#define WIN   1024
#define QKV_N 3072
#define ZSPL  4

__device__ __forceinline__ bf16u f2bf(float f) {
  union { float f; uint32_t u; } v; v.f = f;
  uint32_t r = v.u + 0x7FFFu + ((v.u >> 16) & 1u);
  return (bf16u)(r >> 16);
}
__device__ __forceinline__ float bf2f(bf16u b) {
  union { uint32_t u; float f; } v; v.u = ((uint32_t)b) << 16;
  return v.f;
}

__device__ __forceinline__ void gl2lds16(const void* g, void* l) {
  __builtin_amdgcn_global_load_lds(
      (const __attribute__((address_space(1))) void*)g,
      (__attribute__((address_space(3))) void*)l, 16, 0, 0);
}

// ---------------- fused embedding + rmsnorm ----------------
__global__ __launch_bounds__(256) void embednorm_kernel(const int* __restrict__ tokens,
                                                        const float* __restrict__ table,
                                                        float* __restrict__ x,
                                                        bf16u* __restrict__ nout) {
  int s = blockIdx.x;
  int tok = tokens[s];
  int i0 = threadIdx.x * 8;
  float v[8] = {0,0,0,0,0,0,0,0};
  if (tok != 0) {
    const float* src = table + (size_t)tok * EMB;
    float4 a = *(const float4*)(src + i0);
    float4 b = *(const float4*)(src + i0 + 4);
    v[0]=a.x; v[1]=a.y; v[2]=a.z; v[3]=a.w; v[4]=b.x; v[5]=b.y; v[6]=b.z; v[7]=b.w;
  }
  *(float4*)(x + (size_t)s * EMB + i0)     = make_float4(v[0],v[1],v[2],v[3]);
  *(float4*)(x + (size_t)s * EMB + i0 + 4) = make_float4(v[4],v[5],v[6],v[7]);
  float ss = 0.0f;
  #pragma unroll
  for (int j = 0; j < 8; ++j) ss += v[j] * v[j];
  #pragma unroll
  for (int off = 1; off < 64; off <<= 1) ss += __shfl_xor(ss, off);
  __shared__ float red[4];
  if ((threadIdx.x & 63) == 0) red[threadIdx.x >> 6] = ss;
  __syncthreads();
  float scale = rsqrtf((red[0] + red[1] + red[2] + red[3]) * (1.0f / EMB) + 1e-5f);
  short8 o;
  #pragma unroll
  for (int j = 0; j < 8; ++j) o[j] = (short)f2bf(v[j] * scale);
  *(short8*)(nout + (size_t)s * EMB + i0) = o;
}

// ---------------- rope cos/sin table ----------------
__global__ __launch_bounds__(256) void ropetab_kernel(float* __restrict__ tab) {
  int idx = blockIdx.x * 256 + threadIdx.x;
  int d = idx & 63;
  int s = idx >> 6;
  float ang = (float)s * __powf(10000.0f, -(float)d * (1.0f / 64.0f));
  float si, c;
  sincosf(ang, &si, &c);
  tab[(size_t)s * 128 + d] = c;
  tab[(size_t)s * 128 + 64 + d] = si;
}

// ---------------- rmsnorm (standalone) ----------------
__global__ __launch_bounds__(256) void rmsnorm_kernel(const float* __restrict__ x,
                                                      bf16u* __restrict__ out) {
  int s = blockIdx.x;
  const float* row = x + (size_t)s * EMB;
  int i0 = threadIdx.x * 8;
  float4 a = *(const float4*)(row + i0);
  float4 b = *(const float4*)(row + i0 + 4);
  float ss = a.x*a.x + a.y*a.y + a.z*a.z + a.w*a.w
           + b.x*b.x + b.y*b.y + b.z*b.z + b.w*b.w;
  #pragma unroll
  for (int off = 1; off < 64; off <<= 1) ss += __shfl_xor(ss, off);
  __shared__ float red[4];
  if ((threadIdx.x & 63) == 0) red[threadIdx.x >> 6] = ss;
  __syncthreads();
  float scale = rsqrtf((red[0] + red[1] + red[2] + red[3]) * (1.0f / EMB) + 1e-5f);
  float v[8] = {a.x, a.y, a.z, a.w, b.x, b.y, b.z, b.w};
  short8 o;
  #pragma unroll
  for (int j = 0; j < 8; ++j) o[j] = (short)f2bf(v[j] * scale);
  *(short8*)(out + (size_t)s * EMB + i0) = o;
}

// ---------------- fused split-K reduce + residual + rmsnorm ----------------
__global__ __launch_bounds__(256) void reduce4norm_kernel(float* __restrict__ x,
                                                          const float* __restrict__ p,
                                                          bf16u* __restrict__ nout) {
  int s = blockIdx.x;
  const size_t MN = (size_t)SEQ * EMB;
  size_t base = (size_t)s * EMB + threadIdx.x * 8;
  float v[8];
  #pragma unroll
  for (int h = 0; h < 2; ++h) {
    size_t i = base + h * 4;
    float4 a  = *(const float4*)(x + i);
    float4 b0 = *(const float4*)(p + i);
    float4 b1 = *(const float4*)(p + i + MN);
    float4 b2 = *(const float4*)(p + i + 2 * MN);
    float4 b3 = *(const float4*)(p + i + 3 * MN);
    v[h*4+0] = a.x + b0.x + b1.x + b2.x + b3.x;
    v[h*4+1] = a.y + b0.y + b1.y + b2.y + b3.y;
    v[h*4+2] = a.z + b0.z + b1.z + b2.z + b3.z;
    v[h*4+3] = a.w + b0.w + b1.w + b2.w + b3.w;
    *(float4*)(x + i) = make_float4(v[h*4+0], v[h*4+1], v[h*4+2], v[h*4+3]);
  }
  float ss = 0.0f;
  #pragma unroll
  for (int j = 0; j < 8; ++j) ss += v[j] * v[j];
  #pragma unroll
  for (int off = 1; off < 64; off <<= 1) ss += __shfl_xor(ss, off);
  __shared__ float red[4];
  if ((threadIdx.x & 63) == 0) red[threadIdx.x >> 6] = ss;
  __syncthreads();
  float scale = rsqrtf((red[0] + red[1] + red[2] + red[3]) * (1.0f / EMB) + 1e-5f);
  short8 o;
  #pragma unroll
  for (int j = 0; j < 8; ++j) o[j] = (short)f2bf(v[j] * scale);
  *(short8*)(nout + base) = o;
}

// ---------------- batched transpose + convert, 64x64 tiles, z = layer ----------------
__global__ __launch_bounds__(256) void transp_kernel(const float* __restrict__ in,
                                                     bf16u* __restrict__ out,
                                                     int R, int C, int pairhalf,
                                                     size_t ostride) {
  __shared__ float tile[64][65];
  in  += (size_t)blockIdx.z * R * C;
  out += (size_t)blockIdx.z * ostride;
  int c0 = blockIdx.x * 64, r0 = blockIdx.y * 64;
  int tx = threadIdx.x & 15, ty = threadIdx.x >> 4;
  #pragma unroll
  for (int i = 0; i < 4; ++i) {
    int r = ty + i * 16;
    float4 v = *(const float4*)(in + (size_t)(r0 + r) * C + c0 + tx * 4);
    tile[tx * 4 + 0][r] = v.x;
    tile[tx * 4 + 1][r] = v.y;
    tile[tx * 4 + 2][r] = v.z;
    tile[tx * 4 + 3][r] = v.w;
  }
  __syncthreads();
  int rx = threadIdx.x & 15, cy = threadIdx.x >> 4;
  #pragma unroll
  for (int i = 0; i < 4; ++i) {
    int c = c0 + cy + i * 16;
    int n = pairhalf ? (c < pairhalf ? 2 * c : 2 * (c - pairhalf) + 1) : c;
    short4v o;
    #pragma unroll
    for (int j = 0; j < 4; ++j) o[j] = (short)f2bf(tile[cy + i * 16][rx * 4 + j]);
    *(short4v*)(out + (size_t)n * R + r0 + rx * 4) = o;
  }
}

// ================= 128x128 2-phase GEMM =================
template <int MODE>
__global__ __launch_bounds__(256) void gemm_kernel(const bf16u* __restrict__ A,
                                                   const bf16u* __restrict__ Bt,
                                                   void* __restrict__ C,
                                                   int M, int N, int K) {
  __shared__ __align__(16) char lds[2][2][8192];

  int nx = gridDim.x, ny = gridDim.y;
  int nwg = nx * ny;
  int orig = blockIdx.y * nx + blockIdx.x;
  int q = nwg >> 3, r = nwg & 7;
  int xcd = orig & 7, loc = orig >> 3;
  int id = (xcd < r ? xcd * (q + 1) : r * (q + 1) + (xcd - r) * q) + loc;
  int bx = id / ny, by = id - bx * ny;
  int n0 = bx * 128, m0 = by * 128;

  int t = threadIdx.x;
  int w = t >> 6, l = t & 63;
  int wm = (w >> 1) * 64, wn = (w & 1) * 64;
  int l15 = l & 15, l4 = l >> 4;

  int srow = w * 16 + (l >> 2);
  int scol = (l & 3) * 8;

  f32x4 acc[4][4] = {};

  auto stage = [&](int buf, int k0) {
    #pragma unroll
    for (int i = 0; i < 2; ++i) {
      gl2lds16(A  + (size_t)(m0 + i * 64 + srow) * K + k0 + scol,
               &lds[buf][0][i * 4096 + w * 1024]);
      gl2lds16(Bt + (size_t)(n0 + i * 64 + srow) * K + k0 + scol,
               &lds[buf][1][i * 4096 + w * 1024]);
    }
  };

  auto compute = [&](int buf) {
    short8 af[4], bfr[4];
    #pragma unroll
    for (int i = 0; i < 4; ++i) {
      af[i]  = *(const short8*)(&lds[buf][0][((wm + i * 16 + l15) * 32 + l4 * 8) * 2]);
      bfr[i] = *(const short8*)(&lds[buf][1][((wn + i * 16 + l15) * 32 + l4 * 8) * 2]);
    }
    #pragma unroll
    for (int i = 0; i < 4; ++i)
      #pragma unroll
      for (int j = 0; j < 4; ++j)
        acc[i][j] = __builtin_amdgcn_mfma_f32_16x16x32_bf16(af[i], bfr[j], acc[i][j], 0, 0, 0);
  };

  int nt = K >> 5;
  int cur = 0;
  stage(0, 0);
  __syncthreads();
  for (int tt = 0; tt < nt; ++tt) {
    if (tt + 1 < nt) stage(cur ^ 1, (tt + 1) * 32);
    compute(cur);
    __syncthreads();
    cur ^= 1;
  }

  #pragma unroll
  for (int i = 0; i < 4; ++i)
    #pragma unroll
    for (int j = 0; j < 4; ++j) {
      int col = n0 + wn + j * 16 + l15;
      #pragma unroll
      for (int rr = 0; rr < 4; ++rr) {
        int row = m0 + wm + i * 16 + l4 * 4 + rr;
        float v = acc[i][j][rr];
        if (MODE == 0) {
          ((bf16u*)C)[(size_t)row * N + col] = f2bf(v);
        } else if (MODE == 1) {
          float* p = (float*)C + (size_t)row * N + col;
          *p += v;
        } else {
          ((float*)C)[(size_t)row * N + col] = v;
        }
      }
    }
}

// ================= qkv GEMM with fused RoPE epilogue (register-pair exchange) =================
__global__ __launch_bounds__(256) void qkvgemm_kernel(const bf16u* __restrict__ A,
                                                      const bf16u* __restrict__ Bt,
                                                      const float* __restrict__ tab,
                                                      bf16u* __restrict__ q_bf,
                                                      bf16u* __restrict__ k_bf,
                                                      bf16u* __restrict__ v_bf,
                                                      int M, int N, int K) {
  __shared__ __align__(16) char lds[2][2][8192];

  int nx = gridDim.x, ny = gridDim.y;
  int nwg = nx * ny;
  int orig = blockIdx.y * nx + blockIdx.x;
  int q = nwg >> 3, r = nwg & 7;
  int xcd = orig & 7, loc = orig >> 3;
  int id = (xcd < r ? xcd * (q + 1) : r * (q + 1) + (xcd - r) * q) + loc;
  int bx = id / ny, by = id - bx * ny;
  int n0 = bx * 128, m0 = by * 128;

  int t = threadIdx.x;
  int w = t >> 6, l = t & 63;
  int wm = w * 32;
  int l15 = l & 15, l4 = l >> 4;

  int srow = w * 16 + (l >> 2);
  int scol = (l & 3) * 8;

  f32x4 acc[2][8] = {};

  auto stage = [&](int buf, int k0) {
    #pragma unroll
    for (int i = 0; i < 2; ++i) {
      gl2lds16(A  + (size_t)(m0 + i * 64 + srow) * K + k0 + scol,
               &lds[buf][0][i * 4096 + w * 1024]);
      gl2lds16(Bt + (size_t)(n0 + i * 64 + srow) * K + k0 + scol,
               &lds[buf][1][i * 4096 + w * 1024]);
    }
  };

  auto compute = [&](int buf) {
    short8 af[2], bfr[8];
    #pragma unroll
    for (int i = 0; i < 2; ++i)
      af[i] = *(const short8*)(&lds[buf][0][((wm + i * 16 + l15) * 32 + l4 * 8) * 2]);
    #pragma unroll
    for (int j = 0; j < 8; ++j)
      bfr[j] = *(const short8*)(&lds[buf][1][((j * 16 + l15) * 32 + l4 * 8) * 2]);
    #pragma unroll
    for (int i = 0; i < 2; ++i)
      #pragma unroll
      for (int j = 0; j < 8; ++j)
        acc[i][j] = __builtin_amdgcn_mfma_f32_16x16x32_bf16(af[i], bfr[j], acc[i][j], 0, 0, 0);
  };

  int nt = K >> 5;
  int cur = 0;
  stage(0, 0);
  __syncthreads();
  for (int tt = 0; tt < nt; ++tt) {
    if (tt + 1 < nt) stage(cur ^ 1, (tt + 1) * 32);
    compute(cur);
    __syncthreads();
    cur ^= 1;
  }

  bool isV = (n0 >= 2560);

  #pragma unroll
  for (int i = 0; i < 2; ++i)
    #pragma unroll
    for (int rr = 0; rr < 4; ++rr) {
      int row = m0 + wm + i * 16 + l4 * 4 + rr;
      if (isV) {
        int vh = (n0 - 2560) >> 7;
        bf16u* vrow = v_bf + (((size_t)vh * SEQ + row) << 7);
        #pragma unroll
        for (int j = 0; j < 8; ++j)
          vrow[j * 16 + l15] = f2bf(acc[i][j][rr]);
      } else {
        bf16u* orow;
        if (n0 < 2048) orow = q_bf + ((((size_t)(n0 >> 7)) * SEQ + row) << 7);
        else           orow = k_bf + ((((size_t)((n0 - 2048) >> 7)) * SEQ + row) << 7);
        #pragma unroll
        for (int jj = 0; jj < 4; ++jj) {
          int dm = jj * 16 + l15;
          float c  = tab[(size_t)row * 128 + dm];
          float si = tab[(size_t)row * 128 + 64 + dm];
          float f0 = acc[i][jj][rr];
          float f1 = acc[i][jj + 4][rr];
          orow[dm]      = f2bf(c * f0 - si * f1);
          orow[dm + 64] = f2bf(c * f1 + si * f0);
        }
      }
    }
}

// ================= 256x256 8-phase GEMM (T1+T2+T3+T4+T5) =================
__device__ __forceinline__ void stage_half(const bf16u* __restrict__ p, int ld,
                                           int row0, int k0, char* slotBase, int t) {
  int r  = t >> 3, c8 = t & 7;
  int cs = (c8 ^ (r & 7)) << 3;
  gl2lds16(p + (size_t)(row0 + r) * ld + k0 + cs, slotBase + t * 16);
  gl2lds16(p + (size_t)(row0 + 64 + r) * ld + k0 + cs, slotBase + 8192 + t * 16);
}

template<int KK>
__device__ __forceinline__ short8 read_frag(const char* slot, int row, int l4) {
  int kc = KK * 4 + l4;
  return *(const short8*)(slot + row * 128 + ((kc ^ (row & 7)) << 4));
}

template<int NH>
__device__ __forceinline__ void mfma_quad(f32x4 (&acc)[8][4], const short8 (&a)[8],
                                          short8 b0, short8 b1) {
  __builtin_amdgcn_s_setprio(1);
  #pragma unroll
  for (int mi = 0; mi < 8; ++mi) {
    acc[mi][NH * 2]     = __builtin_amdgcn_mfma_f32_16x16x32_bf16(a[mi], b0, acc[mi][NH * 2], 0, 0, 0);
    acc[mi][NH * 2 + 1] = __builtin_amdgcn_mfma_f32_16x16x32_bf16(a[mi], b1, acc[mi][NH * 2 + 1], 0, 0, 0);
  }
  __builtin_amdgcn_s_setprio(0);
}

template <int MODE>
__global__ __launch_bounds__(512) void gemm256_kernel(const bf16u* __restrict__ A,
                                                      const bf16u* __restrict__ Bt,
                                                      void* __restrict__ C,
                                                      int M, int N, int K, int ldk) {
  __shared__ __align__(16) char lds[131072];

  int koff = blockIdx.z * K;
  A  += koff;
  Bt += koff;
  float* Cz = (float*)C + (size_t)blockIdx.z * M * N;

  int nx = gridDim.x, ny = gridDim.y;
  int nwg = nx * ny;
  int orig = blockIdx.y * nx + blockIdx.x;
  int q8 = nwg >> 3, r8 = nwg & 7;
  int xcd = orig & 7, loc = orig >> 3;
  int id = (xcd < r8 ? xcd * (q8 + 1) : r8 * (q8 + 1) + (xcd - r8) * q8) + loc;
  int bx = id / ny, by = id - bx * ny;
  int n0 = bx * 256, m0 = by * 256;

  int t = threadIdx.x;
  int wid = t >> 6, lane = t & 63;
  int wr = wid >> 2, wc = wid & 3, bh = wc >> 1;
  int l15 = lane & 15, l4 = lane >> 4;

  char* AS0 = lds;              char* AS1 = lds + 16384;
  char* AS2 = lds + 32768;      char* AS3 = lds + 49152;
  char* BS0 = lds + 65536;      char* BS1 = lds + 81920;
  char* BS2 = lds + 98304;      char* BS3 = lds + 114688;

  const char* ASe = lds + wr * 16384;
  const char* ASo = ASe + 32768;
  const char* BSe = lds + 65536 + bh * 16384;
  const char* BSo = BSe + 32768;

  int brow = (wc & 1) * 64;

  f32x4 acc[8][4] = {};
  short8 a[8];
  short8 b0, b1;

  int NT = K >> 6;
  int NI = NT >> 1;

  stage_half(A,  ldk, m0,       0,  AS0, t);
  stage_half(A,  ldk, m0 + 128, 0,  AS1, t);
  stage_half(Bt, ldk, n0,       0,  BS0, t);
  stage_half(Bt, ldk, n0 + 128, 0,  BS1, t);
  stage_half(A,  ldk, m0,       64, AS2, t);
  asm volatile("s_waitcnt vmcnt(2)" ::: "memory");
  __builtin_amdgcn_s_barrier();
  __builtin_amdgcn_sched_barrier(0);

  for (int I = 0; I < NI; ++I) {
    int t0k = I * 128;
    int t1k = t0k + 64;
    bool notlast = (I + 1 < NI);

    #pragma unroll
    for (int mi = 0; mi < 8; ++mi) a[mi] = read_frag<0>(ASe, mi * 16 + l15, l4);
    b0 = read_frag<0>(BSe, brow + l15, l4);
    b1 = read_frag<0>(BSe, brow + 16 + l15, l4);
    stage_half(A, ldk, m0 + 128, t1k, AS3, t);
    __builtin_amdgcn_s_barrier();
    mfma_quad<0>(acc, a, b0, b1);
    __builtin_amdgcn_s_barrier();

    b0 = read_frag<0>(BSe, brow + 32 + l15, l4);
    b1 = read_frag<0>(BSe, brow + 48 + l15, l4);
    stage_half(Bt, ldk, n0, t1k, BS2, t);
    __builtin_amdgcn_s_barrier();
    mfma_quad<1>(acc, a, b0, b1);
    __builtin_amdgcn_s_barrier();

    #pragma unroll
    for (int mi = 0; mi < 8; ++mi) a[mi] = read_frag<1>(ASe, mi * 16 + l15, l4);
    b0 = read_frag<1>(BSe, brow + l15, l4);
    b1 = read_frag<1>(BSe, brow + 16 + l15, l4);
    stage_half(Bt, ldk, n0 + 128, t1k, BS3, t);
    __builtin_amdgcn_s_barrier();
    mfma_quad<0>(acc, a, b0, b1);
    __builtin_amdgcn_s_barrier();

    b0 = read_frag<1>(BSe, brow + 32 + l15, l4);
    b1 = read_frag<1>(BSe, brow + 48 + l15, l4);
    if (notlast) stage_half(A, ldk, m0, t0k + 128, AS0, t);
    if (notlast) { asm volatile("s_waitcnt vmcnt(2)" ::: "memory"); }
    else         { asm volatile("s_waitcnt vmcnt(0)" ::: "memory"); }
    __builtin_amdgcn_s_barrier();
    __builtin_amdgcn_sched_barrier(0);
    mfma_quad<1>(acc, a, b0, b1);
    __builtin_amdgcn_s_barrier();

    #pragma unroll
    for (int mi = 0; mi < 8; ++mi) a[mi] = read_frag<0>(ASo, mi * 16 + l15, l4);
    b0 = read_frag<0>(BSo, brow + l15, l4);
    b1 = read_frag<0>(BSo, brow + 16 + l15, l4);
    if (notlast) stage_half(A, ldk, m0 + 128, t0k + 128, AS1, t);
    __builtin_amdgcn_s_barrier();
    mfma_quad<0>(acc, a, b0, b1);
    __builtin_amdgcn_s_barrier();

    b0 = read_frag<0>(BSo, brow + 32 + l15, l4);
    b1 = read_frag<0>(BSo, brow + 48 + l15, l4);
    if (notlast) stage_half(Bt, ldk, n0, t0k + 128, BS0, t);
    __builtin_amdgcn_s_barrier();
    mfma_quad<1>(acc, a, b0, b1);
    __builtin_amdgcn_s_barrier();

    #pragma unroll
    for (int mi = 0; mi < 8; ++mi) a[mi] = read_frag<1>(ASo, mi * 16 + l15, l4);
    b0 = read_frag<1>(BSo, brow + l15, l4);
    b1 = read_frag<1>(BSo, brow + 16 + l15, l4);
    if (notlast) stage_half(Bt, ldk, n0 + 128, t0k + 128, BS1, t);
    __builtin_amdgcn_s_barrier();
    mfma_quad<0>(acc, a, b0, b1);
    __builtin_amdgcn_s_barrier();

    b0 = read_frag<1>(BSo, brow + 32 + l15, l4);
    b1 = read_frag<1>(BSo, brow + 48 + l15, l4);
    if (notlast) {
      stage_half(A, ldk, m0, t0k + 192, AS2, t);
      asm volatile("s_waitcnt vmcnt(2)" ::: "memory");
    }
    __builtin_amdgcn_s_barrier();
    __builtin_amdgcn_sched_barrier(0);
    mfma_quad<1>(acc, a, b0, b1);
    __builtin_amdgcn_s_barrier();
  }

  #pragma unroll
  for (int mi = 0; mi < 8; ++mi)
    #pragma unroll
    for (int ni = 0; ni < 4; ++ni) {
      int col = n0 + wc * 64 + ni * 16 + l15;
      #pragma unroll
      for (int rr = 0; rr < 4; ++rr) {
        int row = m0 + wr * 128 + mi * 16 + l4 * 4 + rr;
        float v = acc[mi][ni][rr];
        if (MODE == 3) {
          float pv = __shfl_xor(v, 1);
          if ((l15 & 1) == 0) {
            float hval = pv * (v / (1.0f + __expf(-v)));
            ((bf16u*)C)[(size_t)row * HIDN + (col >> 1)] = f2bf(hval);
          }
        } else if (MODE == 2) {
          Cz[(size_t)row * N + col] = v;
        } else if (MODE == 1) {
          float* p = (float*)C + (size_t)row * N + col;
          *p += v;
        } else {
          ((bf16u*)C)[(size_t)row * N + col] = f2bf(v);
        }
      }
    }
}

// ---------------- sliding-window flash attention (QBLK=128, 8 waves, z = KV quarter) ----------------
__global__ __launch_bounds__(512) void attn_kernel(const bf16u* __restrict__ q_bf,
                                                   const bf16u* __restrict__ k_bf,
                                                   const bf16u* __restrict__ v_bf,
                                                   float* __restrict__ opart,
                                                   float* __restrict__ mlbuf) {
  int h = blockIdx.y;
  int q0 = blockIdx.x * 128;
  int z = blockIdx.z;
  int kvh = h >> 2;
  const bf16u* Kp = k_bf + (size_t)kvh * SEQ * DKH;
  const bf16u* Vp = v_bf + (size_t)kvh * SEQ * DKH;

  __shared__ __align__(16) char  Klds[64 * 128 * 2];
  __shared__ __align__(16) bf16u Vlds[128][72];
  __shared__ __align__(16) bf16u Plds[8][16][72];

  int t = threadIdx.x, wave = t >> 6, lane = t & 63;
  int l15 = lane & 15, l4 = lane >> 4;
  int qrow0 = q0 + wave * 16;

  short8 qf[4];
  #pragma unroll
  for (int ks = 0; ks < 4; ++ks)
    qf[ks] = *(const short8*)(q_bf + ((size_t)h * SEQ + qrow0 + l15) * DKH + ks * 32 + l4 * 8);

  f32x4 o[8] = {};
  float m[4], lsum[4];
  #pragma unroll
  for (int r = 0; r < 4; ++r) { m[r] = -INFINITY; lsum[r] = 0.0f; }

  int vkey = t & 63, vd0 = (t >> 6) * 16;

  int jstart = q0 >= WIN ? ((q0 - (WIN - 1)) & ~63) : 0;
  int T  = (q0 + 128 - jstart) >> 6;
  int jb = jstart + ((T * z) >> 2) * 64;
  int je = jstart + ((T * (z + 1)) >> 2) * 64;

  for (int j0 = jb; j0 < je; j0 += 64) {
    __syncthreads();
    #pragma unroll
    for (int i = 0; i < 2; ++i) {
      int c = t + i * 512;
      int key = c >> 4, cc = c & 15;
      int off = key * 256 + cc * 16; off ^= (key & 7) << 4;
      *(short8*)(Klds + off) = *(const short8*)(Kp + (size_t)(j0 + key) * DKH + cc * 8);
    }
    {
      const bf16u* src = Vp + (size_t)(j0 + vkey) * DKH + vd0;
      short8 v0 = *(const short8*)(src);
      short8 v1 = *(const short8*)(src + 8);
      #pragma unroll
      for (int i = 0; i < 8; ++i) Vlds[vd0 + i][vkey] = (bf16u)(unsigned short)v0[i];
      #pragma unroll
      for (int i = 0; i < 8; ++i) Vlds[vd0 + 8 + i][vkey] = (bf16u)(unsigned short)v1[i];
    }
    __syncthreads();

    f32x4 sacc[4] = {};
    #pragma unroll
    for (int nt = 0; nt < 4; ++nt) {
      int key = nt * 16 + l15;
      #pragma unroll
      for (int ks = 0; ks < 4; ++ks) {
        int off = key * 256 + ks * 64 + l4 * 16; off ^= (key & 7) << 4;
        short8 kf = *(short8*)(Klds + off);
        sacc[nt] = __builtin_amdgcn_mfma_f32_16x16x32_bf16(qf[ks], kf, sacc[nt], 0, 0, 0);
      }
    }

    float sv[4][4];
    #pragma unroll
    for (int nt = 0; nt < 4; ++nt) {
      int jk = j0 + nt * 16 + l15;
      #pragma unroll
      for (int r = 0; r < 4; ++r) {
        int iq = qrow0 + l4 * 4 + r;
        float s = sacc[nt][r] * 0.08838834764831845f;
        bool valid = (jk <= iq) && (iq - jk < WIN);
        sv[nt][r] = valid ? s : -1e9f;
      }
    }

    float mxr[4];
    #pragma unroll
    for (int r = 0; r < 4; ++r) {
      float mx = fmaxf(fmaxf(sv[0][r], sv[1][r]), fmaxf(sv[2][r], sv[3][r]));
      #pragma unroll
      for (int off = 1; off < 16; off <<= 1) mx = fmaxf(mx, __shfl_xor(mx, off));
      mxr[r] = mx;
    }

    bool grow = (mxr[0] > m[0] + 8.0f) || (mxr[1] > m[1] + 8.0f) ||
                (mxr[2] > m[2] + 8.0f) || (mxr[3] > m[3] + 8.0f);
    if (__any(grow)) {
      #pragma unroll
      for (int r = 0; r < 4; ++r) {
        float mn = fmaxf(m[r], mxr[r]);
        float alpha = __expf(m[r] - mn);
        m[r] = mn;
        lsum[r] *= alpha;
        #pragma unroll
        for (int d = 0; d < 8; ++d) o[d][r] *= alpha;
      }
    }

    float p[4][4];
    #pragma unroll
    for (int r = 0; r < 4; ++r) {
      float ps = 0.0f;
      #pragma unroll
      for (int nt = 0; nt < 4; ++nt) { p[nt][r] = __expf(sv[nt][r] - m[r]); ps += p[nt][r]; }
      #pragma unroll
      for (int off = 1; off < 16; off <<= 1) ps += __shfl_xor(ps, off);
      lsum[r] += ps;
    }

    #pragma unroll
    for (int nt = 0; nt < 4; ++nt)
      #pragma unroll
      for (int r = 0; r < 4; ++r)
        Plds[wave][l4 * 4 + r][nt * 16 + l15] = f2bf(p[nt][r]);

    #pragma unroll
    for (int kk = 0; kk < 2; ++kk) {
      short8 pf = *(short8*)(&Plds[wave][l15][kk * 32 + l4 * 8]);
      #pragma unroll
      for (int d = 0; d < 8; ++d) {
        short8 vf = *(short8*)(&Vlds[d * 16 + l15][kk * 32 + l4 * 8]);
        o[d] = __builtin_amdgcn_mfma_f32_16x16x32_bf16(pf, vf, o[d], 0, 0, 0);
      }
    }
  }

  float* op = opart + (((size_t)z * NHEAD + h) * SEQ) * DKH;
  #pragma unroll
  for (int d = 0; d < 8; ++d)
    #pragma unroll
    for (int r = 0; r < 4; ++r) {
      int row = qrow0 + l4 * 4 + r;
      op[(size_t)row * DKH + d * 16 + l15] = o[d][r];
    }
  if (l15 == 0) {
    float* ml = mlbuf + ((size_t)z * NHEAD + h) * SEQ * 2;
    #pragma unroll
    for (int r = 0; r < 4; ++r) {
      int row = qrow0 + l4 * 4 + r;
      ml[(size_t)row * 2]     = m[r];
      ml[(size_t)row * 2 + 1] = lsum[r];
    }
  }
}

// ---------------- combine ZSPL KV-slice partials -> attn_b bf16 ----------------
__global__ __launch_bounds__(256) void combine_kernel(const float* __restrict__ opart,
                                                      const float* __restrict__ mlbuf,
                                                      bf16u* __restrict__ attn_out) {
  size_t idx = ((size_t)blockIdx.x * 256 + threadIdx.x) * 4;
  int d4 = (int)(idx & 127);
  int s  = (int)((idx >> 7) & (SEQ - 1));
  int h  = (int)(idx >> 18);
  const size_t OSZ = (size_t)NHEAD * SEQ * DKH;
  const size_t MSZ = (size_t)NHEAD * SEQ * 2;
  size_t obase = ((size_t)h * SEQ + s) * DKH + d4;
  size_t mbase = ((size_t)h * SEQ + s) * 2;

  float mv[ZSPL], lv[ZSPL];
  float ms = -INFINITY;
  #pragma unroll
  for (int z = 0; z < ZSPL; ++z) {
    mv[z] = mlbuf[mbase + z * MSZ];
    lv[z] = mlbuf[mbase + z * MSZ + 1];
    ms = fmaxf(ms, mv[z]);
  }
  float denom = 0.0f;
  float az[ZSPL];
  #pragma unroll
  for (int z = 0; z < ZSPL; ++z) {
    az[z] = __expf(mv[z] - ms);
    denom += az[z] * lv[z];
  }
  float inv = 1.0f / denom;
  float acc0 = 0, acc1 = 0, acc2 = 0, acc3 = 0;
  #pragma unroll
  for (int z = 0; z < ZSPL; ++z) {
    float4 v = *(const float4*)(opart + obase + z * OSZ);
    acc0 += az[z] * v.x; acc1 += az[z] * v.y;
    acc2 += az[z] * v.z; acc3 += az[z] * v.w;
  }
  short4v o;
  o[0] = (short)f2bf(acc0 * inv);
  o[1] = (short)f2bf(acc1 * inv);
  o[2] = (short)f2bf(acc2 * inv);
  o[3] = (short)f2bf(acc3 * inv);
  *(short4v*)(attn_out + (size_t)s * EMB + h * DKH + d4) = o;
}

// ---------------- host ----------------
extern "C" void kernel_launch(void* const* d_in, const int* in_sizes, int n_in,
                              void* d_out, int out_size, void* d_ws, size_t ws_size,
                              hipStream_t stream) {
  const int*   tokens  = (const int*)d_in[0];
  const float* table   = (const float*)d_in[1];
  const float* wq      = (const float*)d_in[2];
  const float* wk      = (const float*)d_in[3];
  const float* wv      = (const float*)d_in[4];
  const float* wo      = (const float*)d_in[5];
  const float* w_up    = (const float*)d_in[6];
  const float* w_down  = (const float*)d_in[7];
  const float* w_vocab = (const float*)d_in[8];
  float* out = (float*)d_out;

  char* base = (char*)d_ws;
  size_t o = 0;
  auto alloc = [&](size_t bytes) { size_t r = o; o += (bytes + 255) & ~(size_t)255; return r; };
  size_t o_x     = alloc((size_t)SEQ * EMB * 4);
  size_t o_nbf   = alloc((size_t)SEQ * EMB * 2);
  size_t o_qkvw  = alloc((size_t)NLAY * QKV_N * EMB * 2);
  size_t o_wot   = alloc((size_t)NLAY * EMB * EMB * 2);
  size_t o_wupt  = alloc((size_t)NLAY * 2 * HIDN * EMB * 2);
  size_t o_wdnt  = alloc((size_t)NLAY * EMB * HIDN * 2);
  size_t o_tab   = alloc((size_t)SEQ * 128 * 4);
  size_t o_qbf   = alloc((size_t)NHEAD * SEQ * DKH * 2);
  size_t o_kbf   = alloc((size_t)NKV * SEQ * DKH * 2);
  size_t o_vbf   = alloc((size_t)NKV * SEQ * DKH * 2);
  size_t o_attn  = alloc((size_t)SEQ * EMB * 2);
  size_t o_big   = alloc((size_t)SEQ * 2 * HIDN * 4);   // attn partials / split-K partials / wvoc_t
  size_t o_hbf   = alloc((size_t)SEQ * HIDN * 2);

  float* x      = (float*)(base + o_x);
  bf16u* n_bf   = (bf16u*)(base + o_nbf);
  bf16u* qkvw_t = (bf16u*)(base + o_qkvw);
  bf16u* wo_t   = (bf16u*)(base + o_wot);
  bf16u* wup_t  = (bf16u*)(base + o_wupt);
  bf16u* wdn_t  = (bf16u*)(base + o_wdnt);
  float* ropetb = (float*)(base + o_tab);
  bf16u* q_bf   = (bf16u*)(base + o_qbf);
  bf16u* k_bf   = (bf16u*)(base + o_kbf);
  bf16u* v_bf   = (bf16u*)(base + o_vbf);
  bf16u* attn_b = (bf16u*)(base + o_attn);
  float* part   = (float*)(base + o_big);
  float* opart  = (float*)(base + o_big);
  float* mlbuf  = (float*)(base + o_big + (size_t)ZSPL * NHEAD * SEQ * DKH * 4);
  bf16u* h_bf   = (bf16u*)(base + o_hbf);
  bf16u* wvoc_t = (bf16u*)(base + o_big);

  const size_t QKVW = (size_t)QKV_N * EMB;

  transp_kernel<<<dim3(EMB / 64, EMB / 64, NLAY), 256, 0, stream>>>(
      wq, qkvw_t, EMB, EMB, 0, QKVW);
  transp_kernel<<<dim3(512 / 64, EMB / 64, NLAY), 256, 0, stream>>>(
      wk, qkvw_t + (size_t)2048 * EMB, EMB, 512, 0, QKVW);
  transp_kernel<<<dim3(512 / 64, EMB / 64, NLAY), 256, 0, stream>>>(
      wv, qkvw_t + (size_t)2560 * EMB, EMB, 512, 0, QKVW);
  transp_kernel<<<dim3(EMB / 64, EMB / 64, NLAY), 256, 0, stream>>>(
      wo, wo_t, EMB, EMB, 0, (size_t)EMB * EMB);
  transp_kernel<<<dim3(2 * HIDN / 64, EMB / 64, NLAY), 256, 0, stream>>>(
      w_up, wup_t, EMB, 2 * HIDN, HIDN, (size_t)2 * HIDN * EMB);
  transp_kernel<<<dim3(EMB / 64, HIDN / 64, NLAY), 256, 0, stream>>>(
      w_down, wdn_t, HIDN, EMB, 0, (size_t)EMB * HIDN);

  ropetab_kernel<<<SEQ * 64 / 256, 256, 0, stream>>>(ropetb);
  embednorm_kernel<<<SEQ, 256, 0, stream>>>(tokens, table, x, n_bf);

  for (int l = 0; l < NLAY; ++l) {
    qkvgemm_kernel<<<dim3(QKV_N / 128, SEQ / 128), 256, 0, stream>>>(
        n_bf, qkvw_t + (size_t)l * QKVW, ropetb, q_bf, k_bf, v_bf, SEQ, QKV_N, EMB);

    attn_kernel<<<dim3(SEQ / 128, NHEAD, ZSPL), 512, 0, stream>>>(
        q_bf, k_bf, v_bf, opart, mlbuf);
    combine_kernel<<<NHEAD * SEQ * DKH / 1024, 256, 0, stream>>>(
        opart, mlbuf, attn_b);

    gemm_kernel<1><<<dim3(EMB / 128, SEQ / 128), 256, 0, stream>>>(
        attn_b, wo_t + (size_t)l * EMB * EMB, x, SEQ, EMB, EMB);

    rmsnorm_kernel<<<SEQ, 256, 0, stream>>>(x, n_bf);
    gemm256_kernel<3><<<dim3(2 * HIDN / 256, SEQ / 256), 512, 0, stream>>>(
        n_bf, wup_t + (size_t)l * 2 * HIDN * EMB, h_bf, SEQ, 2 * HIDN, EMB, EMB);
    gemm256_kernel<2><<<dim3(EMB / 256, SEQ / 256, 4), 512, 0, stream>>>(
        h_bf, wdn_t + (size_t)l * EMB * HIDN, part, SEQ, EMB, 2048, HIDN);
    reduce4norm_kernel<<<SEQ, 256, 0, stream>>>(x, part, n_bf);
  }

  transp_kernel<<<dim3(NVOC / 64, EMB / 64, 1), 256, 0, stream>>>(
      w_vocab, wvoc_t, EMB, NVOC, 0, 0);
  gemm256_kernel<2><<<dim3(NVOC / 256, SEQ / 256), 512, 0, stream>>>(
      n_bf, wvoc_t, out, SEQ, NVOC, EMB, EMB);
}

// Round 14
// 2252.344 us; speedup vs baseline: 1.0201x; 1.0201x over previous
//
#include <hip/hip_runtime.h>
#include <cstdint>

typedef unsigned short bf16u;
typedef __attribute__((ext_vector_type(8))) short short8;
typedef __attribute__((ext_vector_type(4))) short short4v;
typedef __attribute__((ext_vector_type(4))) float f32x4;

#define SEQ   2048
#define EMB   2048
#define NHEAD 16
#define NKV   4
#define DKH   128
#define HIDN  8192
#define NVOC  32000
#define NLAY  4
#define WIN   1024
#define QKV_N 3072
#define ZSPL  2

__device__ __forceinline__ bf16u f2bf(float f) {
  union { float f; uint32_t u; } v; v.f = f;
  uint32_t r = v.u + 0x7FFFu + ((v.u >> 16) & 1u);
  return (bf16u)(r >> 16);
}
__device__ __forceinline__ float bf2f(bf16u b) {
  union { uint32_t u; float f; } v; v.u = ((uint32_t)b) << 16;
  return v.f;
}

__device__ __forceinline__ void gl2lds16(const void* g, void* l) {
  __builtin_amdgcn_global_load_lds(
      (const __attribute__((address_space(1))) void*)g,
      (__attribute__((address_space(3))) void*)l, 16, 0, 0);
}

// ---------------- fused embedding + rmsnorm ----------------
__global__ __launch_bounds__(256) void embednorm_kernel(const int* __restrict__ tokens,
                                                        const float* __restrict__ table,
                                                        float* __restrict__ x,
                                                        bf16u* __restrict__ nout) {
  int s = blockIdx.x;
  int tok = tokens[s];
  int i0 = threadIdx.x * 8;
  float v[8] = {0,0,0,0,0,0,0,0};
  if (tok != 0) {
    const float* src = table + (size_t)tok * EMB;
    float4 a = *(const float4*)(src + i0);
    float4 b = *(const float4*)(src + i0 + 4);
    v[0]=a.x; v[1]=a.y; v[2]=a.z; v[3]=a.w; v[4]=b.x; v[5]=b.y; v[6]=b.z; v[7]=b.w;
  }
  *(float4*)(x + (size_t)s * EMB + i0)     = make_float4(v[0],v[1],v[2],v[3]);
  *(float4*)(x + (size_t)s * EMB + i0 + 4) = make_float4(v[4],v[5],v[6],v[7]);
  float ss = 0.0f;
  #pragma unroll
  for (int j = 0; j < 8; ++j) ss += v[j] * v[j];
  #pragma unroll
  for (int off = 1; off < 64; off <<= 1) ss += __shfl_xor(ss, off);
  __shared__ float red[4];
  if ((threadIdx.x & 63) == 0) red[threadIdx.x >> 6] = ss;
  __syncthreads();
  float scale = rsqrtf((red[0] + red[1] + red[2] + red[3]) * (1.0f / EMB) + 1e-5f);
  short8 o;
  #pragma unroll
  for (int j = 0; j < 8; ++j) o[j] = (short)f2bf(v[j] * scale);
  *(short8*)(nout + (size_t)s * EMB + i0) = o;
}

// ---------------- rope cos/sin table ----------------
__global__ __launch_bounds__(256) void ropetab_kernel(float* __restrict__ tab) {
  int idx = blockIdx.x * 256 + threadIdx.x;
  int d = idx & 63;
  int s = idx >> 6;
  float ang = (float)s * __powf(10000.0f, -(float)d * (1.0f / 64.0f));
  float si, c;
  sincosf(ang, &si, &c);
  tab[(size_t)s * 128 + d] = c;
  tab[(size_t)s * 128 + 64 + d] = si;
}

// ---------------- rmsnorm (standalone) ----------------
__global__ __launch_bounds__(256) void rmsnorm_kernel(const float* __restrict__ x,
                                                      bf16u* __restrict__ out) {
  int s = blockIdx.x;
  const float* row = x + (size_t)s * EMB;
  int i0 = threadIdx.x * 8;
  float4 a = *(const float4*)(row + i0);
  float4 b = *(const float4*)(row + i0 + 4);
  float ss = a.x*a.x + a.y*a.y + a.z*a.z + a.w*a.w
           + b.x*b.x + b.y*b.y + b.z*b.z + b.w*b.w;
  #pragma unroll
  for (int off = 1; off < 64; off <<= 1) ss += __shfl_xor(ss, off);
  __shared__ float red[4];
  if ((threadIdx.x & 63) == 0) red[threadIdx.x >> 6] = ss;
  __syncthreads();
  float scale = rsqrtf((red[0] + red[1] + red[2] + red[3]) * (1.0f / EMB) + 1e-5f);
  float v[8] = {a.x, a.y, a.z, a.w, b.x, b.y, b.z, b.w};
  short8 o;
  #pragma unroll
  for (int j = 0; j < 8; ++j) o[j] = (short)f2bf(v[j] * scale);
  *(short8*)(out + (size_t)s * EMB + i0) = o;
}

// ---------------- fused split-K reduce + residual + rmsnorm ----------------
__global__ __launch_bounds__(256) void reduce4norm_kernel(float* __restrict__ x,
                                                          const float* __restrict__ p,
                                                          bf16u* __restrict__ nout) {
  int s = blockIdx.x;
  const size_t MN = (size_t)SEQ * EMB;
  size_t base = (size_t)s * EMB + threadIdx.x * 8;
  float v[8];
  #pragma unroll
  for (int h = 0; h < 2; ++h) {
    size_t i = base + h * 4;
    float4 a  = *(const float4*)(x + i);
    float4 b0 = *(const float4*)(p + i);
    float4 b1 = *(const float4*)(p + i + MN);
    float4 b2 = *(const float4*)(p + i + 2 * MN);
    float4 b3 = *(const float4*)(p + i + 3 * MN);
    v[h*4+0] = a.x + b0.x + b1.x + b2.x + b3.x;
    v[h*4+1] = a.y + b0.y + b1.y + b2.y + b3.y;
    v[h*4+2] = a.z + b0.z + b1.z + b2.z + b3.z;
    v[h*4+3] = a.w + b0.w + b1.w + b2.w + b3.w;
    *(float4*)(x + i) = make_float4(v[h*4+0], v[h*4+1], v[h*4+2], v[h*4+3]);
  }
  float ss = 0.0f;
  #pragma unroll
  for (int j = 0; j < 8; ++j) ss += v[j] * v[j];
  #pragma unroll
  for (int off = 1; off < 64; off <<= 1) ss += __shfl_xor(ss, off);
  __shared__ float red[4];
  if ((threadIdx.x & 63) == 0) red[threadIdx.x >> 6] = ss;
  __syncthreads();
  float scale = rsqrtf((red[0] + red[1] + red[2] + red[3]) * (1.0f / EMB) + 1e-5f);
  short8 o;
  #pragma unroll
  for (int j = 0; j < 8; ++j) o[j] = (short)f2bf(v[j] * scale);
  *(short8*)(nout + base) = o;
}

// ---------------- batched transpose + convert, 64x64 tiles, z = layer ----------------
__global__ __launch_bounds__(256) void transp_kernel(const float* __restrict__ in,
                                                     bf16u* __restrict__ out,
                                                     int R, int C, int pairhalf,
                                                     size_t ostride) {
  __shared__ float tile[64][65];
  in  += (size_t)blockIdx.z * R * C;
  out += (size_t)blockIdx.z * ostride;
  int c0 = blockIdx.x * 64, r0 = blockIdx.y * 64;
  int tx = threadIdx.x & 15, ty = threadIdx.x >> 4;
  #pragma unroll
  for (int i = 0; i < 4; ++i) {
    int r = ty + i * 16;
    float4 v = *(const float4*)(in + (size_t)(r0 + r) * C + c0 + tx * 4);
    tile[tx * 4 + 0][r] = v.x;
    tile[tx * 4 + 1][r] = v.y;
    tile[tx * 4 + 2][r] = v.z;
    tile[tx * 4 + 3][r] = v.w;
  }
  __syncthreads();
  int rx = threadIdx.x & 15, cy = threadIdx.x >> 4;
  #pragma unroll
  for (int i = 0; i < 4; ++i) {
    int c = c0 + cy + i * 16;
    int n = pairhalf ? (c < pairhalf ? 2 * c : 2 * (c - pairhalf) + 1) : c;
    short4v o;
    #pragma unroll
    for (int j = 0; j < 4; ++j) o[j] = (short)f2bf(tile[cy + i * 16][rx * 4 + j]);
    *(short4v*)(out + (size_t)n * R + r0 + rx * 4) = o;
  }
}

// ================= 128x128 2-phase GEMM =================
template <int MODE>
__global__ __launch_bounds__(256) void gemm_kernel(const bf16u* __restrict__ A,
                                                   const bf16u* __restrict__ Bt,
                                                   void* __restrict__ C,
                                                   int M, int N, int K) {
  __shared__ __align__(16) char lds[2][2][8192];

  int nx = gridDim.x, ny = gridDim.y;
  int nwg = nx * ny;
  int orig = blockIdx.y * nx + blockIdx.x;
  int q = nwg >> 3, r = nwg & 7;
  int xcd = orig & 7, loc = orig >> 3;
  int id = (xcd < r ? xcd * (q + 1) : r * (q + 1) + (xcd - r) * q) + loc;
  int bx = id / ny, by = id - bx * ny;
  int n0 = bx * 128, m0 = by * 128;

  int t = threadIdx.x;
  int w = t >> 6, l = t & 63;
  int wm = (w >> 1) * 64, wn = (w & 1) * 64;
  int l15 = l & 15, l4 = l >> 4;

  int srow = w * 16 + (l >> 2);
  int scol = (l & 3) * 8;

  f32x4 acc[4][4] = {};

  auto stage = [&](int buf, int k0) {
    #pragma unroll
    for (int i = 0; i < 2; ++i) {
      gl2lds16(A  + (size_t)(m0 + i * 64 + srow) * K + k0 + scol,
               &lds[buf][0][i * 4096 + w * 1024]);
      gl2lds16(Bt + (size_t)(n0 + i * 64 + srow) * K + k0 + scol,
               &lds[buf][1][i * 4096 + w * 1024]);
    }
  };

  auto compute = [&](int buf) {
    short8 af[4], bfr[4];
    #pragma unroll
    for (int i = 0; i < 4; ++i) {
      af[i]  = *(const short8*)(&lds[buf][0][((wm + i * 16 + l15) * 32 + l4 * 8) * 2]);
      bfr[i] = *(const short8*)(&lds[buf][1][((wn + i * 16 + l15) * 32 + l4 * 8) * 2]);
    }
    #pragma unroll
    for (int i = 0; i < 4; ++i)
      #pragma unroll
      for (int j = 0; j < 4; ++j)
        acc[i][j] = __builtin_amdgcn_mfma_f32_16x16x32_bf16(af[i], bfr[j], acc[i][j], 0, 0, 0);
  };

  int nt = K >> 5;
  int cur = 0;
  stage(0, 0);
  __syncthreads();
  for (int tt = 0; tt < nt; ++tt) {
    if (tt + 1 < nt) stage(cur ^ 1, (tt + 1) * 32);
    compute(cur);
    __syncthreads();
    cur ^= 1;
  }

  #pragma unroll
  for (int i = 0; i < 4; ++i)
    #pragma unroll
    for (int j = 0; j < 4; ++j) {
      int col = n0 + wn + j * 16 + l15;
      #pragma unroll
      for (int rr = 0; rr < 4; ++rr) {
        int row = m0 + wm + i * 16 + l4 * 4 + rr;
        float v = acc[i][j][rr];
        if (MODE == 0) {
          ((bf16u*)C)[(size_t)row * N + col] = f2bf(v);
        } else if (MODE == 1) {
          float* p = (float*)C + (size_t)row * N + col;
          *p += v;
        } else {
          ((float*)C)[(size_t)row * N + col] = v;
        }
      }
    }
}

// ================= qkv GEMM with fused RoPE epilogue (register-pair exchange) =================
__global__ __launch_bounds__(256) void qkvgemm_kernel(const bf16u* __restrict__ A,
                                                      const bf16u* __restrict__ Bt,
                                                      const float* __restrict__ tab,
                                                      bf16u* __restrict__ q_bf,
                                                      bf16u* __restrict__ k_bf,
                                                      bf16u* __restrict__ v_bf,
                                                      int M, int N, int K) {
  __shared__ __align__(16) char lds[2][2][8192];

  int nx = gridDim.x, ny = gridDim.y;
  int nwg = nx * ny;
  int orig = blockIdx.y * nx + blockIdx.x;
  int q = nwg >> 3, r = nwg & 7;
  int xcd = orig & 7, loc = orig >> 3;
  int id = (xcd < r ? xcd * (q + 1) : r * (q + 1) + (xcd - r) * q) + loc;
  int bx = id / ny, by = id - bx * ny;
  int n0 = bx * 128, m0 = by * 128;

  int t = threadIdx.x;
  int w = t >> 6, l = t & 63;
  int wm = w * 32;
  int l15 = l & 15, l4 = l >> 4;

  int srow = w * 16 + (l >> 2);
  int scol = (l & 3) * 8;

  f32x4 acc[2][8] = {};

  auto stage = [&](int buf, int k0) {
    #pragma unroll
    for (int i = 0; i < 2; ++i) {
      gl2lds16(A  + (size_t)(m0 + i * 64 + srow) * K + k0 + scol,
               &lds[buf][0][i * 4096 + w * 1024]);
      gl2lds16(Bt + (size_t)(n0 + i * 64 + srow) * K + k0 + scol,
               &lds[buf][1][i * 4096 + w * 1024]);
    }
  };

  auto compute = [&](int buf) {
    short8 af[2], bfr[8];
    #pragma unroll
    for (int i = 0; i < 2; ++i)
      af[i] = *(const short8*)(&lds[buf][0][((wm + i * 16 + l15) * 32 + l4 * 8) * 2]);
    #pragma unroll
    for (int j = 0; j < 8; ++j)
      bfr[j] = *(const short8*)(&lds[buf][1][((j * 16 + l15) * 32 + l4 * 8) * 2]);
    #pragma unroll
    for (int i = 0; i < 2; ++i)
      #pragma unroll
      for (int j = 0; j < 8; ++j)
        acc[i][j] = __builtin_amdgcn_mfma_f32_16x16x32_bf16(af[i], bfr[j], acc[i][j], 0, 0, 0);
  };

  int nt = K >> 5;
  int cur = 0;
  stage(0, 0);
  __syncthreads();
  for (int tt = 0; tt < nt; ++tt) {
    if (tt + 1 < nt) stage(cur ^ 1, (tt + 1) * 32);
    compute(cur);
    __syncthreads();
    cur ^= 1;
  }

  bool isV = (n0 >= 2560);

  #pragma unroll
  for (int i = 0; i < 2; ++i)
    #pragma unroll
    for (int rr = 0; rr < 4; ++rr) {
      int row = m0 + wm + i * 16 + l4 * 4 + rr;
      if (isV) {
        int vh = (n0 - 2560) >> 7;
        bf16u* vrow = v_bf + (((size_t)vh * SEQ + row) << 7);
        #pragma unroll
        for (int j = 0; j < 8; ++j)
          vrow[j * 16 + l15] = f2bf(acc[i][j][rr]);
      } else {
        bf16u* orow;
        if (n0 < 2048) orow = q_bf + ((((size_t)(n0 >> 7)) * SEQ + row) << 7);
        else           orow = k_bf + ((((size_t)((n0 - 2048) >> 7)) * SEQ + row) << 7);
        #pragma unroll
        for (int jj = 0; jj < 4; ++jj) {
          int dm = jj * 16 + l15;
          float c  = tab[(size_t)row * 128 + dm];
          float si = tab[(size_t)row * 128 + 64 + dm];
          float f0 = acc[i][jj][rr];
          float f1 = acc[i][jj + 4][rr];
          orow[dm]      = f2bf(c * f0 - si * f1);
          orow[dm + 64] = f2bf(c * f1 + si * f0);
        }
      }
    }
}

// ================= 256x256 8-phase GEMM (T1+T2+T3+T4+T5) =================
__device__ __forceinline__ void stage_half(const bf16u* __restrict__ p, int ld,
                                           int row0, int k0, char* slotBase, int t) {
  int r  = t >> 3, c8 = t & 7;
  int cs = (c8 ^ (r & 7)) << 3;
  gl2lds16(p + (size_t)(row0 + r) * ld + k0 + cs, slotBase + t * 16);
  gl2lds16(p + (size_t)(row0 + 64 + r) * ld + k0 + cs, slotBase + 8192 + t * 16);
}

template<int KK>
__device__ __forceinline__ short8 read_frag(const char* slot, int row, int l4) {
  int kc = KK * 4 + l4;
  return *(const short8*)(slot + row * 128 + ((kc ^ (row & 7)) << 4));
}

template<int NH>
__device__ __forceinline__ void mfma_quad(f32x4 (&acc)[8][4], const short8 (&a)[8],
                                          short8 b0, short8 b1) {
  __builtin_amdgcn_s_setprio(1);
  #pragma unroll
  for (int mi = 0; mi < 8; ++mi) {
    acc[mi][NH * 2]     = __builtin_amdgcn_mfma_f32_16x16x32_bf16(a[mi], b0, acc[mi][NH * 2], 0, 0, 0);
    acc[mi][NH * 2 + 1] = __builtin_amdgcn_mfma_f32_16x16x32_bf16(a[mi], b1, acc[mi][NH * 2 + 1], 0, 0, 0);
  }
  __builtin_amdgcn_s_setprio(0);
}

template <int MODE>
__global__ __launch_bounds__(512) void gemm256_kernel(const bf16u* __restrict__ A,
                                                      const bf16u* __restrict__ Bt,
                                                      void* __restrict__ C,
                                                      int M, int N, int K, int ldk) {
  __shared__ __align__(16) char lds[131072];

  int koff = blockIdx.z * K;
  A  += koff;
  Bt += koff;
  float* Cz = (float*)C + (size_t)blockIdx.z * M * N;

  int nx = gridDim.x, ny = gridDim.y;
  int nwg = nx * ny;
  int orig = blockIdx.y * nx + blockIdx.x;
  int q8 = nwg >> 3, r8 = nwg & 7;
  int xcd = orig & 7, loc = orig >> 3;
  int id = (xcd < r8 ? xcd * (q8 + 1) : r8 * (q8 + 1) + (xcd - r8) * q8) + loc;
  int bx = id / ny, by = id - bx * ny;
  int n0 = bx * 256, m0 = by * 256;

  int t = threadIdx.x;
  int wid = t >> 6, lane = t & 63;
  int wr = wid >> 2, wc = wid & 3, bh = wc >> 1;
  int l15 = lane & 15, l4 = lane >> 4;

  char* AS0 = lds;              char* AS1 = lds + 16384;
  char* AS2 = lds + 32768;      char* AS3 = lds + 49152;
  char* BS0 = lds + 65536;      char* BS1 = lds + 81920;
  char* BS2 = lds + 98304;      char* BS3 = lds + 114688;

  const char* ASe = lds + wr * 16384;
  const char* ASo = ASe + 32768;
  const char* BSe = lds + 65536 + bh * 16384;
  const char* BSo = BSe + 32768;

  int brow = (wc & 1) * 64;

  f32x4 acc[8][4] = {};
  short8 a[8];
  short8 b0, b1;

  int NT = K >> 6;
  int NI = NT >> 1;

  stage_half(A,  ldk, m0,       0,  AS0, t);
  stage_half(A,  ldk, m0 + 128, 0,  AS1, t);
  stage_half(Bt, ldk, n0,       0,  BS0, t);
  stage_half(Bt, ldk, n0 + 128, 0,  BS1, t);
  stage_half(A,  ldk, m0,       64, AS2, t);
  asm volatile("s_waitcnt vmcnt(2)" ::: "memory");
  __builtin_amdgcn_s_barrier();
  __builtin_amdgcn_sched_barrier(0);

  for (int I = 0; I < NI; ++I) {
    int t0k = I * 128;
    int t1k = t0k + 64;
    bool notlast = (I + 1 < NI);

    #pragma unroll
    for (int mi = 0; mi < 8; ++mi) a[mi] = read_frag<0>(ASe, mi * 16 + l15, l4);
    b0 = read_frag<0>(BSe, brow + l15, l4);
    b1 = read_frag<0>(BSe, brow + 16 + l15, l4);
    stage_half(A, ldk, m0 + 128, t1k, AS3, t);
    __builtin_amdgcn_s_barrier();
    mfma_quad<0>(acc, a, b0, b1);
    __builtin_amdgcn_s_barrier();

    b0 = read_frag<0>(BSe, brow + 32 + l15, l4);
    b1 = read_frag<0>(BSe, brow + 48 + l15, l4);
    stage_half(Bt, ldk, n0, t1k, BS2, t);
    __builtin_amdgcn_s_barrier();
    mfma_quad<1>(acc, a, b0, b1);
    __builtin_amdgcn_s_barrier();

    #pragma unroll
    for (int mi = 0; mi < 8; ++mi) a[mi] = read_frag<1>(ASe, mi * 16 + l15, l4);
    b0 = read_frag<1>(BSe, brow + l15, l4);
    b1 = read_frag<1>(BSe, brow + 16 + l15, l4);
    stage_half(Bt, ldk, n0 + 128, t1k, BS3, t);
    __builtin_amdgcn_s_barrier();
    mfma_quad<0>(acc, a, b0, b1);
    __builtin_amdgcn_s_barrier();

    b0 = read_frag<1>(BSe, brow + 32 + l15, l4);
    b1 = read_frag<1>(BSe, brow + 48 + l15, l4);
    if (notlast) stage_half(A, ldk, m0, t0k + 128, AS0, t);
    if (notlast) { asm volatile("s_waitcnt vmcnt(2)" ::: "memory"); }
    else         { asm volatile("s_waitcnt vmcnt(0)" ::: "memory"); }
    __builtin_amdgcn_s_barrier();
    __builtin_amdgcn_sched_barrier(0);
    mfma_quad<1>(acc, a, b0, b1);
    __builtin_amdgcn_s_barrier();

    #pragma unroll
    for (int mi = 0; mi < 8; ++mi) a[mi] = read_frag<0>(ASo, mi * 16 + l15, l4);
    b0 = read_frag<0>(BSo, brow + l15, l4);
    b1 = read_frag<0>(BSo, brow + 16 + l15, l4);
    if (notlast) stage_half(A, ldk, m0 + 128, t0k + 128, AS1, t);
    __builtin_amdgcn_s_barrier();
    mfma_quad<0>(acc, a, b0, b1);
    __builtin_amdgcn_s_barrier();

    b0 = read_frag<0>(BSo, brow + 32 + l15, l4);
    b1 = read_frag<0>(BSo, brow + 48 + l15, l4);
    if (notlast) stage_half(Bt, ldk, n0, t0k + 128, BS0, t);
    __builtin_amdgcn_s_barrier();
    mfma_quad<1>(acc, a, b0, b1);
    __builtin_amdgcn_s_barrier();

    #pragma unroll
    for (int mi = 0; mi < 8; ++mi) a[mi] = read_frag<1>(ASo, mi * 16 + l15, l4);
    b0 = read_frag<1>(BSo, brow + l15, l4);
    b1 = read_frag<1>(BSo, brow + 16 + l15, l4);
    if (notlast) stage_half(Bt, ldk, n0 + 128, t0k + 128, BS1, t);
    __builtin_amdgcn_s_barrier();
    mfma_quad<0>(acc, a, b0, b1);
    __builtin_amdgcn_s_barrier();

    b0 = read_frag<1>(BSo, brow + 32 + l15, l4);
    b1 = read_frag<1>(BSo, brow + 48 + l15, l4);
    if (notlast) {
      stage_half(A, ldk, m0, t0k + 192, AS2, t);
      asm volatile("s_waitcnt vmcnt(2)" ::: "memory");
    }
    __builtin_amdgcn_s_barrier();
    __builtin_amdgcn_sched_barrier(0);
    mfma_quad<1>(acc, a, b0, b1);
    __builtin_amdgcn_s_barrier();
  }

  #pragma unroll
  for (int mi = 0; mi < 8; ++mi)
    #pragma unroll
    for (int ni = 0; ni < 4; ++ni) {
      int col = n0 + wc * 64 + ni * 16 + l15;
      #pragma unroll
      for (int rr = 0; rr < 4; ++rr) {
        int row = m0 + wr * 128 + mi * 16 + l4 * 4 + rr;
        float v = acc[mi][ni][rr];
        if (MODE == 3) {
          float pv = __shfl_xor(v, 1);
          if ((l15 & 1) == 0) {
            float hval = pv * (v / (1.0f + __expf(-v)));
            ((bf16u*)C)[(size_t)row * HIDN + (col >> 1)] = f2bf(hval);
          }
        } else if (MODE == 2) {
          Cz[(size_t)row * N + col] = v;
        } else if (MODE == 1) {
          float* p = (float*)C + (size_t)row * N + col;
          *p += v;
        } else {
          ((bf16u*)C)[(size_t)row * N + col] = f2bf(v);
        }
      }
    }
}

// ---------------- sliding-window flash attention (QBLK=128, 8 waves, z = KV half) ----------------
__global__ __launch_bounds__(512) void attn_kernel(const bf16u* __restrict__ q_bf,
                                                   const bf16u* __restrict__ k_bf,
                                                   const bf16u* __restrict__ v_bf,
                                                   float* __restrict__ opart,
                                                   float* __restrict__ mlbuf) {
  int h = blockIdx.y;
  int q0 = blockIdx.x * 128;
  int z = blockIdx.z;
  int kvh = h >> 2;
  const bf16u* Kp = k_bf + (size_t)kvh * SEQ * DKH;
  const bf16u* Vp = v_bf + (size_t)kvh * SEQ * DKH;

  __shared__ __align__(16) char  Klds[64 * 128 * 2];
  __shared__ __align__(16) bf16u Vlds[128][72];
  __shared__ __align__(16) bf16u Plds[8][16][72];

  int t = threadIdx.x, wave = t >> 6, lane = t & 63;
  int l15 = lane & 15, l4 = lane >> 4;
  int qrow0 = q0 + wave * 16;

  short8 qf[4];
  #pragma unroll
  for (int ks = 0; ks < 4; ++ks)
    qf[ks] = *(const short8*)(q_bf + ((size_t)h * SEQ + qrow0 + l15) * DKH + ks * 32 + l4 * 8);

  f32x4 o[8] = {};
  float m[4], lsum[4];
  #pragma unroll
  for (int r = 0; r < 4; ++r) { m[r] = -INFINITY; lsum[r] = 0.0f; }

  int vkey = t & 63, vd0 = (t >> 6) * 16;

  int jstart = q0 >= WIN ? ((q0 - (WIN - 1)) & ~63) : 0;
  int T  = (q0 + 128 - jstart) >> 6;
  int jb = jstart + ((T * z) / ZSPL) * 64;
  int je = jstart + ((T * (z + 1)) / ZSPL) * 64;

  for (int j0 = jb; j0 < je; j0 += 64) {
    __syncthreads();
    #pragma unroll
    for (int i = 0; i < 2; ++i) {
      int c = t + i * 512;
      int key = c >> 4, cc = c & 15;
      int off = key * 256 + cc * 16; off ^= (key & 7) << 4;
      *(short8*)(Klds + off) = *(const short8*)(Kp + (size_t)(j0 + key) * DKH + cc * 8);
    }
    {
      const bf16u* src = Vp + (size_t)(j0 + vkey) * DKH + vd0;
      short8 v0 = *(const short8*)(src);
      short8 v1 = *(const short8*)(src + 8);
      #pragma unroll
      for (int i = 0; i < 8; ++i) Vlds[vd0 + i][vkey] = (bf16u)(unsigned short)v0[i];
      #pragma unroll
      for (int i = 0; i < 8; ++i) Vlds[vd0 + 8 + i][vkey] = (bf16u)(unsigned short)v1[i];
    }
    __syncthreads();

    f32x4 sacc[4] = {};
    #pragma unroll
    for (int nt = 0; nt < 4; ++nt) {
      int key = nt * 16 + l15;
      #pragma unroll
      for (int ks = 0; ks < 4; ++ks) {
        int off = key * 256 + ks * 64 + l4 * 16; off ^= (key & 7) << 4;
        short8 kf = *(short8*)(Klds + off);
        sacc[nt] = __builtin_amdgcn_mfma_f32_16x16x32_bf16(qf[ks], kf, sacc[nt], 0, 0, 0);
      }
    }

    float sv[4][4];
    #pragma unroll
    for (int nt = 0; nt < 4; ++nt) {
      int jk = j0 + nt * 16 + l15;
      #pragma unroll
      for (int r = 0; r < 4; ++r) {
        int iq = qrow0 + l4 * 4 + r;
        float s = sacc[nt][r] * 0.08838834764831845f;
        bool valid = (jk <= iq) && (iq - jk < WIN);
        sv[nt][r] = valid ? s : -1e9f;
      }
    }

    float mxr[4];
    #pragma unroll
    for (int r = 0; r < 4; ++r) {
      float mx = fmaxf(fmaxf(sv[0][r], sv[1][r]), fmaxf(sv[2][r], sv[3][r]));
      #pragma unroll
      for (int off = 1; off < 16; off <<= 1) mx = fmaxf(mx, __shfl_xor(mx, off));
      mxr[r] = mx;
    }

    bool grow = (mxr[0] > m[0] + 8.0f) || (mxr[1] > m[1] + 8.0f) ||
                (mxr[2] > m[2] + 8.0f) || (mxr[3] > m[3] + 8.0f);
    if (__any(grow)) {
      #pragma unroll
      for (int r = 0; r < 4; ++r) {
        float mn = fmaxf(m[r], mxr[r]);
        float alpha = __expf(m[r] - mn);
        m[r] = mn;
        lsum[r] *= alpha;
        #pragma unroll
        for (int d = 0; d < 8; ++d) o[d][r] *= alpha;
      }
    }

    float p[4][4];
    #pragma unroll
    for (int r = 0; r < 4; ++r) {
      float ps = 0.0f;
      #pragma unroll
      for (int nt = 0; nt < 4; ++nt) { p[nt][r] = __expf(sv[nt][r] - m[r]); ps += p[nt][r]; }
      #pragma unroll
      for (int off = 1; off < 16; off <<= 1) ps += __shfl_xor(ps, off);
      lsum[r] += ps;
    }

    #pragma unroll
    for (int nt = 0; nt < 4; ++nt)
      #pragma unroll
      for (int r = 0; r < 4; ++r)
        Plds[wave][l4 * 4 + r][nt * 16 + l15] = f2bf(p[nt][r]);

    #pragma unroll
    for (int kk = 0; kk < 2; ++kk) {
      short8 pf = *(short8*)(&Plds[wave][l15][kk * 32 + l4 * 8]);
      #pragma unroll
      for (int d = 0; d < 8; ++d) {
        short8 vf = *(short8*)(&Vlds[d * 16 + l15][kk * 32 + l4 * 8]);
        o[d] = __builtin_amdgcn_mfma_f32_16x16x32_bf16(pf, vf, o[d], 0, 0, 0);
      }
    }
  }

  float* op = opart + (((size_t)z * NHEAD + h) * SEQ) * DKH;
  #pragma unroll
  for (int d = 0; d < 8; ++d)
    #pragma unroll
    for (int r = 0; r < 4; ++r) {
      int row = qrow0 + l4 * 4 + r;
      op[(size_t)row * DKH + d * 16 + l15] = o[d][r];
    }
  if (l15 == 0) {
    float* ml = mlbuf + ((size_t)z * NHEAD + h) * SEQ * 2;
    #pragma unroll
    for (int r = 0; r < 4; ++r) {
      int row = qrow0 + l4 * 4 + r;
      ml[(size_t)row * 2]     = m[r];
      ml[(size_t)row * 2 + 1] = lsum[r];
    }
  }
}

// ---------------- combine ZSPL KV-slice partials -> attn_b bf16 ----------------
__global__ __launch_bounds__(256) void combine_kernel(const float* __restrict__ opart,
                                                      const float* __restrict__ mlbuf,
                                                      bf16u* __restrict__ attn_out) {
  size_t idx = ((size_t)blockIdx.x * 256 + threadIdx.x) * 4;
  int d4 = (int)(idx & 127);
  int s  = (int)((idx >> 7) & (SEQ - 1));
  int h  = (int)(idx >> 18);
  const size_t OSZ = (size_t)NHEAD * SEQ * DKH;
  const size_t MSZ = (size_t)NHEAD * SEQ * 2;
  size_t obase = ((size_t)h * SEQ + s) * DKH + d4;
  size_t mbase = ((size_t)h * SEQ + s) * 2;

  float mv[ZSPL], lv[ZSPL];
  float ms = -INFINITY;
  #pragma unroll
  for (int z = 0; z < ZSPL; ++z) {
    mv[z] = mlbuf[mbase + z * MSZ];
    lv[z] = mlbuf[mbase + z * MSZ + 1];
    ms = fmaxf(ms, mv[z]);
  }
  float denom = 0.0f;
  float az[ZSPL];
  #pragma unroll
  for (int z = 0; z < ZSPL; ++z) {
    az[z] = __expf(mv[z] - ms);
    denom += az[z] * lv[z];
  }
  float inv = 1.0f / denom;
  float acc0 = 0, acc1 = 0, acc2 = 0, acc3 = 0;
  #pragma unroll
  for (int z = 0; z < ZSPL; ++z) {
    float4 v = *(const float4*)(opart + obase + z * OSZ);
    acc0 += az[z] * v.x; acc1 += az[z] * v.y;
    acc2 += az[z] * v.z; acc3 += az[z] * v.w;
  }
  short4v o;
  o[0] = (short)f2bf(acc0 * inv);
  o[1] = (short)f2bf(acc1 * inv);
  o[2] = (short)f2bf(acc2 * inv);
  o[3] = (short)f2bf(acc3 * inv);
  *(short4v*)(attn_out + (size_t)s * EMB + h * DKH + d4) = o;
}

// ---------------- host ----------------
extern "C" void kernel_launch(void* const* d_in, const int* in_sizes, int n_in,
                              void* d_out, int out_size, void* d_ws, size_t ws_size,
                              hipStream_t stream) {
  const int*   tokens  = (const int*)d_in[0];
  const float* table   = (const float*)d_in[1];
  const float* wq      = (const float*)d_in[2];
  const float* wk      = (const float*)d_in[3];
  const float* wv      = (const float*)d_in[4];
  const float* wo      = (const float*)d_in[5];
  const float* w_up    = (const float*)d_in[6];
  const float* w_down  = (const float*)d_in[7];
  const float* w_vocab = (const float*)d_in[8];
  float* out = (float*)d_out;

  char* base = (char*)d_ws;
  size_t o = 0;
  auto alloc = [&](size_t bytes) { size_t r = o; o += (bytes + 255) & ~(size_t)255; return r; };
  size_t o_x     = alloc((size_t)SEQ * EMB * 4);
  size_t o_nbf   = alloc((size_t)SEQ * EMB * 2);
  size_t o_qkvw  = alloc((size_t)NLAY * QKV_N * EMB * 2);
  size_t o_wot   = alloc((size_t)NLAY * EMB * EMB * 2);
  size_t o_wupt  = alloc((size_t)NLAY * 2 * HIDN * EMB * 2);
  size_t o_wdnt  = alloc((size_t)NLAY * EMB * HIDN * 2);
  size_t o_tab   = alloc((size_t)SEQ * 128 * 4);
  size_t o_qbf   = alloc((size_t)NHEAD * SEQ * DKH * 2);
  size_t o_kbf   = alloc((size_t)NKV * SEQ * DKH * 2);
  size_t o_vbf   = alloc((size_t)NKV * SEQ * DKH * 2);
  size_t o_attn  = alloc((size_t)SEQ * EMB * 2);
  size_t o_big   = alloc((size_t)SEQ * 2 * HIDN * 4);   // attn partials / split-K partials / wvoc_t
  size_t o_hbf   = alloc((size_t)SEQ * HIDN * 2);

  float* x      = (float*)(base + o_x);
  bf16u* n_bf   = (bf16u*)(base + o_nbf);
  bf16u* qkvw_t = (bf16u*)(base + o_qkvw);
  bf16u* wo_t   = (bf16u*)(base + o_wot);
  bf16u* wup_t  = (bf16u*)(base + o_wupt);
  bf16u* wdn_t  = (bf16u*)(base + o_wdnt);
  float* ropetb = (float*)(base + o_tab);
  bf16u* q_bf   = (bf16u*)(base + o_qbf);
  bf16u* k_bf   = (bf16u*)(base + o_kbf);
  bf16u* v_bf   = (bf16u*)(base + o_vbf);
  bf16u* attn_b = (bf16u*)(base + o_attn);
  float* part   = (float*)(base + o_big);
  float* opart  = (float*)(base + o_big);
  float* mlbuf  = (float*)(base + o_big + (size_t)ZSPL * NHEAD * SEQ * DKH * 4);
  bf16u* h_bf   = (bf16u*)(base + o_hbf);
  bf16u* wvoc_t = (bf16u*)(base + o_big);

  const size_t QKVW = (size_t)QKV_N * EMB;

  transp_kernel<<<dim3(EMB / 64, EMB / 64, NLAY), 256, 0, stream>>>(
      wq, qkvw_t, EMB, EMB, 0, QKVW);
  transp_kernel<<<dim3(512 / 64, EMB / 64, NLAY), 256, 0, stream>>>(
      wk, qkvw_t + (size_t)2048 * EMB, EMB, 512, 0, QKVW);
  transp_kernel<<<dim3(512 / 64, EMB / 64, NLAY), 256, 0, stream>>>(
      wv, qkvw_t + (size_t)2560 * EMB, EMB, 512, 0, QKVW);
  transp_kernel<<<dim3(EMB / 64, EMB / 64, NLAY), 256, 0, stream>>>(
      wo, wo_t, EMB, EMB, 0, (size_t)EMB * EMB);
  transp_kernel<<<dim3(2 * HIDN / 64, EMB / 64, NLAY), 256, 0, stream>>>(
      w_up, wup_t, EMB, 2 * HIDN, HIDN, (size_t)2 * HIDN * EMB);
  transp_kernel<<<dim3(EMB / 64, HIDN / 64, NLAY), 256, 0, stream>>>(
      w_down, wdn_t, HIDN, EMB, 0, (size_t)EMB * HIDN);

  ropetab_kernel<<<SEQ * 64 / 256, 256, 0, stream>>>(ropetb);
  embednorm_kernel<<<SEQ, 256, 0, stream>>>(tokens, table, x, n_bf);

  for (int l = 0; l < NLAY; ++l) {
    qkvgemm_kernel<<<dim3(QKV_N / 128, SEQ / 128), 256, 0, stream>>>(
        n_bf, qkvw_t + (size_t)l * QKVW, ropetb, q_bf, k_bf, v_bf, SEQ, QKV_N, EMB);

    attn_kernel<<<dim3(SEQ / 128, NHEAD, ZSPL), 512, 0, stream>>>(
        q_bf, k_bf, v_bf, opart, mlbuf);
    combine_kernel<<<NHEAD * SEQ * DKH / 1024, 256, 0, stream>>>(
        opart, mlbuf, attn_b);

    gemm_kernel<1><<<dim3(EMB / 128, SEQ / 128), 256, 0, stream>>>(
        attn_b, wo_t + (size_t)l * EMB * EMB, x, SEQ, EMB, EMB);

    rmsnorm_kernel<<<SEQ, 256, 0, stream>>>(x, n_bf);
    gemm256_kernel<3><<<dim3(2 * HIDN / 256, SEQ / 256), 512, 0, stream>>>(
        n_bf, wup_t + (size_t)l * 2 * HIDN * EMB, h_bf, SEQ, 2 * HIDN, EMB, EMB);
    gemm256_kernel<2><<<dim3(EMB / 256, SEQ / 256, 4), 512, 0, stream>>>(
        h_bf, wdn_t + (size_t)l * EMB * HIDN, part, SEQ, EMB, 2048, HIDN);
    reduce4norm_kernel<<<SEQ, 256, 0, stream>>>(x, part, n_bf);
  }

  transp_kernel<<<dim3(NVOC / 64, EMB / 64, 1), 256, 0, stream>>>(
      w_vocab, wvoc_t, EMB, NVOC, 0, 0);
  gemm256_kernel<2><<<dim3(NVOC / 256, SEQ / 256), 512, 0, stream>>>(
      n_bf, wvoc_t, out, SEQ, NVOC, EMB, EMB);
}